// Round 1
// baseline (291.527 us; speedup 1.0000x reference)
//
#include <hip/hip_runtime.h>

#define INV_SQRT_2F 0.70710678118654752440f

// ---------------------------------------------------------------------------
// Kernel 1: per-node channel mix.  y[b,n,o,v] = sum_i W[o,i] * x[b,n,i,v]
// One block per (b,node). Threads 0..63 compute W_src rows, 64..127 W_dst rows.
// x tile (64 ch x 3 vec = 192 floats) staged in LDS; W rows read as float4
// (16 KB each, L1-resident after first touch).
// ---------------------------------------------------------------------------
__global__ void __launch_bounds__(128)
node_transform(const float* __restrict__ x,
               const float* __restrict__ W_src,
               const float* __restrict__ W_dst,
               float* __restrict__ y_src,
               float* __restrict__ y_dst,
               int bn_total)
{
    __shared__ float xs[192];
    int bn = blockIdx.x;
    if (bn >= bn_total) return;

    const float4* xp = (const float4*)(x + (size_t)bn * 192);
    int t = threadIdx.x;
    if (t < 48) ((float4*)xs)[t] = xp[t];   // 192 floats = 48 float4
    __syncthreads();

    int o = t & 63;
    const float* W = (t < 64) ? W_src : W_dst;
    float*       y = (t < 64) ? y_src : y_dst;

    const float4* Wrow = (const float4*)(W + o * 64);
    float a0 = 0.f, a1 = 0.f, a2 = 0.f;
#pragma unroll
    for (int i4 = 0; i4 < 16; ++i4) {
        float4 w = Wrow[i4];
        int i = i4 * 4;
        a0 = fmaf(w.x, xs[(i + 0) * 3 + 0], a0);
        a1 = fmaf(w.x, xs[(i + 0) * 3 + 1], a1);
        a2 = fmaf(w.x, xs[(i + 0) * 3 + 2], a2);
        a0 = fmaf(w.y, xs[(i + 1) * 3 + 0], a0);
        a1 = fmaf(w.y, xs[(i + 1) * 3 + 1], a1);
        a2 = fmaf(w.y, xs[(i + 1) * 3 + 2], a2);
        a0 = fmaf(w.z, xs[(i + 2) * 3 + 0], a0);
        a1 = fmaf(w.z, xs[(i + 2) * 3 + 1], a1);
        a2 = fmaf(w.z, xs[(i + 2) * 3 + 2], a2);
        a0 = fmaf(w.w, xs[(i + 3) * 3 + 0], a0);
        a1 = fmaf(w.w, xs[(i + 3) * 3 + 1], a1);
        a2 = fmaf(w.w, xs[(i + 3) * 3 + 2], a2);
    }
    float* yp = y + (size_t)bn * 192 + o * 3;
    yp[0] = a0;
    yp[1] = a1;
    yp[2] = a2;
}

// ---------------------------------------------------------------------------
// Kernel 2: edge gather + add + scale, fully vectorized (float4).
// One work item = one float4 (16 B) of one edge's 768-B row; both batches
// handled per item so src/dst index loads amortize 2x.
// ---------------------------------------------------------------------------
__global__ void __launch_bounds__(256)
edge_combine(const float* __restrict__ y_src,
             const float* __restrict__ y_dst,
             const int* __restrict__ src,
             const int* __restrict__ dst,
             float* __restrict__ out,
             int edges, int nodes)
{
    const int total  = edges * 48;               // 48 float4 per edge row
    const int stride = gridDim.x * blockDim.x;
    const float4* ys = (const float4*)y_src;
    const float4* yd = (const float4*)y_dst;
    float4*       o4 = (float4*)out;

    for (int t = blockIdx.x * blockDim.x + threadIdx.x; t < total; t += stride) {
        int e = t / 48;
        int j = t - e * 48;
        int s = src[e];
        int d = dst[e];

        // batch 0
        float4 a = ys[(size_t)s * 48 + j];
        float4 b = yd[(size_t)d * 48 + j];
        float4 r0;
        r0.x = (a.x + b.x) * INV_SQRT_2F;
        r0.y = (a.y + b.y) * INV_SQRT_2F;
        r0.z = (a.z + b.z) * INV_SQRT_2F;
        r0.w = (a.w + b.w) * INV_SQRT_2F;
        o4[(size_t)e * 48 + j] = r0;

        // batch 1
        float4 c = ys[((size_t)nodes + s) * 48 + j];
        float4 f = yd[((size_t)nodes + d) * 48 + j];
        float4 r1;
        r1.x = (c.x + f.x) * INV_SQRT_2F;
        r1.y = (c.y + f.y) * INV_SQRT_2F;
        r1.z = (c.z + f.z) * INV_SQRT_2F;
        r1.w = (c.w + f.w) * INV_SQRT_2F;
        o4[((size_t)edges + e) * 48 + j] = r1;
    }
}

// ---------------------------------------------------------------------------
// Fallback (only if ws_size is too small): fused per-edge matmul. Correct but
// compute-bound (~31.5 GFLOP fp32).
// ---------------------------------------------------------------------------
__global__ void __launch_bounds__(64)
edge_fused(const float* __restrict__ x,
           const float* __restrict__ W_src,
           const float* __restrict__ W_dst,
           const int* __restrict__ src,
           const int* __restrict__ dst,
           float* __restrict__ out,
           int edges, int nodes)
{
    __shared__ float xs[192];
    __shared__ float xd[192];
    int be = blockIdx.x;
    int b  = be / edges;
    int e  = be - b * edges;
    int s  = src[e];
    int d  = dst[e];
    const float* xps = x + ((size_t)b * nodes + s) * 192;
    const float* xpd = x + ((size_t)b * nodes + d) * 192;
    int t = threadIdx.x;
#pragma unroll
    for (int k = 0; k < 3; ++k) {
        xs[t + 64 * k] = xps[t + 64 * k];
        xd[t + 64 * k] = xpd[t + 64 * k];
    }
    __syncthreads();
    float a0 = 0.f, a1 = 0.f, a2 = 0.f;
#pragma unroll
    for (int i = 0; i < 64; ++i) {
        float ws = W_src[t * 64 + i];
        float wd = W_dst[t * 64 + i];
        a0 += ws * xs[i * 3 + 0] + wd * xd[i * 3 + 0];
        a1 += ws * xs[i * 3 + 1] + wd * xd[i * 3 + 1];
        a2 += ws * xs[i * 3 + 2] + wd * xd[i * 3 + 2];
    }
    float* op = out + ((size_t)b * edges + e) * 192 + t * 3;
    op[0] = a0 * INV_SQRT_2F;
    op[1] = a1 * INV_SQRT_2F;
    op[2] = a2 * INV_SQRT_2F;
}

extern "C" void kernel_launch(void* const* d_in, const int* in_sizes, int n_in,
                              void* d_out, int out_size, void* d_ws, size_t ws_size,
                              hipStream_t stream)
{
    const float* x     = (const float*)d_in[0];
    const float* W_src = (const float*)d_in[1];
    const float* W_dst = (const float*)d_in[2];
    const int*   src   = (const int*)d_in[3];
    const int*   dst   = (const int*)d_in[4];
    float*       out   = (float*)d_out;

    const int batch = 2;
    const int edges = in_sizes[3];
    const int nodes = in_sizes[0] / (batch * 192);   // 192 = dim_in * 3

    const size_t y_elems = (size_t)batch * nodes * 192;
    const size_t needed  = 2 * y_elems * sizeof(float);

    if (ws_size >= needed) {
        float* y_src = (float*)d_ws;
        float* y_dst = y_src + y_elems;
        const int bn_total = batch * nodes;
        node_transform<<<bn_total, 128, 0, stream>>>(x, W_src, W_dst,
                                                     y_src, y_dst, bn_total);
        edge_combine<<<2048, 256, 0, stream>>>(y_src, y_dst, src, dst, out,
                                               edges, nodes);
    } else {
        edge_fused<<<batch * edges, 64, 0, stream>>>(x, W_src, W_dst,
                                                     src, dst, out, edges, nodes);
    }
}

// Round 3
// 278.100 us; speedup vs baseline: 1.0483x; 1.0483x over previous
//
#include <hip/hip_runtime.h>

#define INV_SQRT_2F 0.70710678118654752440f

typedef float fvec4 __attribute__((ext_vector_type(4)));

// ---------------------------------------------------------------------------
// Kernel 1: per-node channel mix.  y[b,n,o,v] = sum_i W[o,i] * x[b,n,i,v]
// One block per (b,node). Threads 0..63 compute W_src rows, 64..127 W_dst rows.
// Workspace layout is BATCH-INTERLEAVED per node: y[node][batch][192] so the
// edge kernel's per-edge gather touches contiguous 1536 B per node.
// ---------------------------------------------------------------------------
__global__ void __launch_bounds__(128)
node_transform(const float* __restrict__ x,
               const float* __restrict__ W_src,
               const float* __restrict__ W_dst,
               float* __restrict__ y_src,
               float* __restrict__ y_dst,
               int nodes, int bn_total)
{
    __shared__ float xs[192];
    int bn = blockIdx.x;               // bn = b*nodes + n  (x is [b][n][192])
    if (bn >= bn_total) return;
    int b = bn / nodes;
    int n = bn - b * nodes;

    const float4* xp = (const float4*)(x + (size_t)bn * 192);
    int t = threadIdx.x;
    if (t < 48) ((float4*)xs)[t] = xp[t];   // 192 floats = 48 float4
    __syncthreads();

    int o = t & 63;
    const float* W = (t < 64) ? W_src : W_dst;
    float*       y = (t < 64) ? y_src : y_dst;

    const float4* Wrow = (const float4*)(W + o * 64);
    float a0 = 0.f, a1 = 0.f, a2 = 0.f;
#pragma unroll
    for (int i4 = 0; i4 < 16; ++i4) {
        float4 w = Wrow[i4];
        int i = i4 * 4;
        a0 = fmaf(w.x, xs[(i + 0) * 3 + 0], a0);
        a1 = fmaf(w.x, xs[(i + 0) * 3 + 1], a1);
        a2 = fmaf(w.x, xs[(i + 0) * 3 + 2], a2);
        a0 = fmaf(w.y, xs[(i + 1) * 3 + 0], a0);
        a1 = fmaf(w.y, xs[(i + 1) * 3 + 1], a1);
        a2 = fmaf(w.y, xs[(i + 1) * 3 + 2], a2);
        a0 = fmaf(w.z, xs[(i + 2) * 3 + 0], a0);
        a1 = fmaf(w.z, xs[(i + 2) * 3 + 1], a1);
        a2 = fmaf(w.z, xs[(i + 2) * 3 + 2], a2);
        a0 = fmaf(w.w, xs[(i + 3) * 3 + 0], a0);
        a1 = fmaf(w.w, xs[(i + 3) * 3 + 1], a1);
        a2 = fmaf(w.w, xs[(i + 3) * 3 + 2], a2);
    }
    // batch-interleaved: row = n*2 + b
    float* yp = y + ((size_t)n * 2 + b) * 192 + o * 3;
    yp[0] = a0;
    yp[1] = a1;
    yp[2] = a2;
}

// ---------------------------------------------------------------------------
// Kernel 2: edge gather + add + scale.  Non-temporal float4 stores so the
// 491 MB output stream does not evict the 30.7 MB y arrays from L2/L3.
// One work item = one float4 slot (j in [0,48)) of one edge; both batches
// handled per item (contiguous 2x768 B per gathered node row).
// ---------------------------------------------------------------------------
__global__ void __launch_bounds__(256)
edge_combine(const float* __restrict__ y_src,
             const float* __restrict__ y_dst,
             const int* __restrict__ src,
             const int* __restrict__ dst,
             float* __restrict__ out,
             int edges)
{
    const int total  = edges * 48;               // 48 float4 per edge row
    const int stride = gridDim.x * blockDim.x;
    const fvec4* ys = (const fvec4*)y_src;
    const fvec4* yd = (const fvec4*)y_dst;
    fvec4*       o4 = (fvec4*)out;

    for (int t = blockIdx.x * blockDim.x + threadIdx.x; t < total; t += stride) {
        int e = t / 48;
        int j = t - e * 48;
        size_t sbase = (size_t)src[e] * 96 + j;  // 96 float4 = 2 batches
        size_t dbase = (size_t)dst[e] * 96 + j;

        // batch 0
        fvec4 a = ys[sbase];
        fvec4 b = yd[dbase];
        fvec4 r0 = (a + b) * INV_SQRT_2F;
        __builtin_nontemporal_store(r0, &o4[(size_t)e * 48 + j]);

        // batch 1
        fvec4 c = ys[sbase + 48];
        fvec4 f = yd[dbase + 48];
        fvec4 r1 = (c + f) * INV_SQRT_2F;
        __builtin_nontemporal_store(r1, &o4[((size_t)edges + e) * 48 + j]);
    }
}

// ---------------------------------------------------------------------------
// Fallback (only if ws_size is too small): fused per-edge matmul.
// ---------------------------------------------------------------------------
__global__ void __launch_bounds__(64)
edge_fused(const float* __restrict__ x,
           const float* __restrict__ W_src,
           const float* __restrict__ W_dst,
           const int* __restrict__ src,
           const int* __restrict__ dst,
           float* __restrict__ out,
           int edges, int nodes)
{
    __shared__ float xs[192];
    __shared__ float xd[192];
    int be = blockIdx.x;
    int b  = be / edges;
    int e  = be - b * edges;
    int s  = src[e];
    int d  = dst[e];
    const float* xps = x + ((size_t)b * nodes + s) * 192;
    const float* xpd = x + ((size_t)b * nodes + d) * 192;
    int t = threadIdx.x;
#pragma unroll
    for (int k = 0; k < 3; ++k) {
        xs[t + 64 * k] = xps[t + 64 * k];
        xd[t + 64 * k] = xpd[t + 64 * k];
    }
    __syncthreads();
    float a0 = 0.f, a1 = 0.f, a2 = 0.f;
#pragma unroll
    for (int i = 0; i < 64; ++i) {
        float ws = W_src[t * 64 + i];
        float wd = W_dst[t * 64 + i];
        a0 += ws * xs[i * 3 + 0] + wd * xd[i * 3 + 0];
        a1 += ws * xs[i * 3 + 1] + wd * xd[i * 3 + 1];
        a2 += ws * xs[i * 3 + 2] + wd * xd[i * 3 + 2];
    }
    float* op = out + ((size_t)b * edges + e) * 192 + t * 3;
    op[0] = a0 * INV_SQRT_2F;
    op[1] = a1 * INV_SQRT_2F;
    op[2] = a2 * INV_SQRT_2F;
}

extern "C" void kernel_launch(void* const* d_in, const int* in_sizes, int n_in,
                              void* d_out, int out_size, void* d_ws, size_t ws_size,
                              hipStream_t stream)
{
    const float* x     = (const float*)d_in[0];
    const float* W_src = (const float*)d_in[1];
    const float* W_dst = (const float*)d_in[2];
    const int*   src   = (const int*)d_in[3];
    const int*   dst   = (const int*)d_in[4];
    float*       out   = (float*)d_out;

    const int batch = 2;
    const int edges = in_sizes[3];
    const int nodes = in_sizes[0] / (batch * 192);   // 192 = dim_in * 3

    const size_t y_elems = (size_t)batch * nodes * 192;
    const size_t needed  = 2 * y_elems * sizeof(float);

    if (ws_size >= needed) {
        float* y_src = (float*)d_ws;
        float* y_dst = y_src + y_elems;
        const int bn_total = batch * nodes;
        node_transform<<<bn_total, 128, 0, stream>>>(x, W_src, W_dst,
                                                     y_src, y_dst, nodes, bn_total);
        edge_combine<<<2048, 256, 0, stream>>>(y_src, y_dst, src, dst, out, edges);
    } else {
        edge_fused<<<batch * edges, 64, 0, stream>>>(x, W_src, W_dst,
                                                     src, dst, out, edges, nodes);
    }
}

// Round 4
// 216.550 us; speedup vs baseline: 1.3462x; 1.2842x over previous
//
#include <hip/hip_runtime.h>

#define INV_SQRT_2F 0.70710678118654752440f

typedef float fvec4 __attribute__((ext_vector_type(4)));

// fp32 -> bf16 bits, round-to-nearest-even (inputs are normal floats here).
static __device__ __forceinline__ unsigned short f2bf(float f)
{
    unsigned int u = __float_as_uint(f);
    u += 0x7fffu + ((u >> 16) & 1u);
    return (unsigned short)(u >> 16);
}

// ---------------------------------------------------------------------------
// Kernel 1: per-node channel mix.  y[b,n,o,v] = sum_i W[o,i] * x[b,n,i,v]
// One block per (b,node). Threads 0..63 -> W_src rows, 64..127 -> W_dst rows.
// y stored as bf16, batch-interleaved per node: y[node][batch][192] so each
// edge gather touches one contiguous 768 B region per node per array.
// ---------------------------------------------------------------------------
__global__ void __launch_bounds__(128)
node_transform(const float* __restrict__ x,
               const float* __restrict__ W_src,
               const float* __restrict__ W_dst,
               unsigned short* __restrict__ y_src,
               unsigned short* __restrict__ y_dst,
               int nodes, int bn_total)
{
    __shared__ float xs[192];
    int bn = blockIdx.x;               // bn = b*nodes + n  (x is [b][n][192])
    if (bn >= bn_total) return;
    int b = bn / nodes;
    int n = bn - b * nodes;

    const float4* xp = (const float4*)(x + (size_t)bn * 192);
    int t = threadIdx.x;
    if (t < 48) ((float4*)xs)[t] = xp[t];   // 192 floats = 48 float4
    __syncthreads();

    int o = t & 63;
    const float*    W = (t < 64) ? W_src : W_dst;
    unsigned short* y = (t < 64) ? y_src : y_dst;

    const float4* Wrow = (const float4*)(W + o * 64);
    float a0 = 0.f, a1 = 0.f, a2 = 0.f;
#pragma unroll
    for (int i4 = 0; i4 < 16; ++i4) {
        float4 w = Wrow[i4];
        int i = i4 * 4;
        a0 = fmaf(w.x, xs[(i + 0) * 3 + 0], a0);
        a1 = fmaf(w.x, xs[(i + 0) * 3 + 1], a1);
        a2 = fmaf(w.x, xs[(i + 0) * 3 + 2], a2);
        a0 = fmaf(w.y, xs[(i + 1) * 3 + 0], a0);
        a1 = fmaf(w.y, xs[(i + 1) * 3 + 1], a1);
        a2 = fmaf(w.y, xs[(i + 1) * 3 + 2], a2);
        a0 = fmaf(w.z, xs[(i + 2) * 3 + 0], a0);
        a1 = fmaf(w.z, xs[(i + 2) * 3 + 1], a1);
        a2 = fmaf(w.z, xs[(i + 2) * 3 + 2], a2);
        a0 = fmaf(w.w, xs[(i + 3) * 3 + 0], a0);
        a1 = fmaf(w.w, xs[(i + 3) * 3 + 1], a1);
        a2 = fmaf(w.w, xs[(i + 3) * 3 + 2], a2);
    }
    // batch-interleaved bf16: row = n*2 + b, 192 elems per (node,batch)
    unsigned short* yp = y + ((size_t)n * 2 + b) * 192 + o * 3;
    yp[0] = f2bf(a0);
    yp[1] = f2bf(a1);
    yp[2] = f2bf(a2);
}

// ---------------------------------------------------------------------------
// Kernel 2: edge gather (bf16) + add + scale -> fp32 out (non-temporal).
// Thread item = 4 output floats (one float4 of out, one uint2 = 4 bf16 of y),
// both batches per item so index loads amortize 2x.
// ---------------------------------------------------------------------------
__global__ void __launch_bounds__(256)
edge_combine(const unsigned short* __restrict__ y_src,
             const unsigned short* __restrict__ y_dst,
             const int* __restrict__ src,
             const int* __restrict__ dst,
             float* __restrict__ out,
             int edges)
{
    const int total  = edges * 48;               // 48 quads per edge row
    const int stride = gridDim.x * blockDim.x;
    const uint2* ys = (const uint2*)y_src;       // 1 uint2 = 4 bf16
    const uint2* yd = (const uint2*)y_dst;
    fvec4*       o4 = (fvec4*)out;

    for (int t = blockIdx.x * blockDim.x + threadIdx.x; t < total; t += stride) {
        int e = t / 48;
        int j = t - e * 48;
        size_t sb = (size_t)src[e] * 96 + j;     // 96 uint2 per node (2 batches)
        size_t db = (size_t)dst[e] * 96 + j;

        uint2 a0 = ys[sb];
        uint2 b0 = yd[db];
        uint2 a1 = ys[sb + 48];
        uint2 b1 = yd[db + 48];

        fvec4 r0, r1;
        r0.x = (__uint_as_float(a0.x << 16)          + __uint_as_float(b0.x << 16))          * INV_SQRT_2F;
        r0.y = (__uint_as_float(a0.x & 0xffff0000u)  + __uint_as_float(b0.x & 0xffff0000u))  * INV_SQRT_2F;
        r0.z = (__uint_as_float(a0.y << 16)          + __uint_as_float(b0.y << 16))          * INV_SQRT_2F;
        r0.w = (__uint_as_float(a0.y & 0xffff0000u)  + __uint_as_float(b0.y & 0xffff0000u))  * INV_SQRT_2F;
        r1.x = (__uint_as_float(a1.x << 16)          + __uint_as_float(b1.x << 16))          * INV_SQRT_2F;
        r1.y = (__uint_as_float(a1.x & 0xffff0000u)  + __uint_as_float(b1.x & 0xffff0000u))  * INV_SQRT_2F;
        r1.z = (__uint_as_float(a1.y << 16)          + __uint_as_float(b1.y << 16))          * INV_SQRT_2F;
        r1.w = (__uint_as_float(a1.y & 0xffff0000u)  + __uint_as_float(b1.y & 0xffff0000u))  * INV_SQRT_2F;

        __builtin_nontemporal_store(r0, &o4[(size_t)e * 48 + j]);
        __builtin_nontemporal_store(r1, &o4[((size_t)edges + e) * 48 + j]);
    }
}

// ---------------------------------------------------------------------------
// Fallback (only if ws_size is too small): fused per-edge matmul, fp32.
// ---------------------------------------------------------------------------
__global__ void __launch_bounds__(64)
edge_fused(const float* __restrict__ x,
           const float* __restrict__ W_src,
           const float* __restrict__ W_dst,
           const int* __restrict__ src,
           const int* __restrict__ dst,
           float* __restrict__ out,
           int edges, int nodes)
{
    __shared__ float xs[192];
    __shared__ float xd[192];
    int be = blockIdx.x;
    int b  = be / edges;
    int e  = be - b * edges;
    int s  = src[e];
    int d  = dst[e];
    const float* xps = x + ((size_t)b * nodes + s) * 192;
    const float* xpd = x + ((size_t)b * nodes + d) * 192;
    int t = threadIdx.x;
#pragma unroll
    for (int k = 0; k < 3; ++k) {
        xs[t + 64 * k] = xps[t + 64 * k];
        xd[t + 64 * k] = xpd[t + 64 * k];
    }
    __syncthreads();
    float a0 = 0.f, a1 = 0.f, a2 = 0.f;
#pragma unroll
    for (int i = 0; i < 64; ++i) {
        float ws = W_src[t * 64 + i];
        float wd = W_dst[t * 64 + i];
        a0 += ws * xs[i * 3 + 0] + wd * xd[i * 3 + 0];
        a1 += ws * xs[i * 3 + 1] + wd * xd[i * 3 + 1];
        a2 += ws * xs[i * 3 + 2] + wd * xd[i * 3 + 2];
    }
    float* op = out + ((size_t)b * edges + e) * 192 + t * 3;
    op[0] = a0 * INV_SQRT_2F;
    op[1] = a1 * INV_SQRT_2F;
    op[2] = a2 * INV_SQRT_2F;
}

extern "C" void kernel_launch(void* const* d_in, const int* in_sizes, int n_in,
                              void* d_out, int out_size, void* d_ws, size_t ws_size,
                              hipStream_t stream)
{
    const float* x     = (const float*)d_in[0];
    const float* W_src = (const float*)d_in[1];
    const float* W_dst = (const float*)d_in[2];
    const int*   src   = (const int*)d_in[3];
    const int*   dst   = (const int*)d_in[4];
    float*       out   = (float*)d_out;

    const int batch = 2;
    const int edges = in_sizes[3];
    const int nodes = in_sizes[0] / (batch * 192);   // 192 = dim_in * 3

    const size_t y_elems = (size_t)batch * nodes * 192;        // per array
    const size_t needed  = 2 * y_elems * sizeof(unsigned short);

    if (ws_size >= needed) {
        unsigned short* y_src = (unsigned short*)d_ws;
        unsigned short* y_dst = y_src + y_elems;
        const int bn_total = batch * nodes;
        node_transform<<<bn_total, 128, 0, stream>>>(x, W_src, W_dst,
                                                     y_src, y_dst, nodes, bn_total);
        edge_combine<<<2048, 256, 0, stream>>>(y_src, y_dst, src, dst, out, edges);
    } else {
        edge_fused<<<batch * edges, 64, 0, stream>>>(x, W_src, W_dst,
                                                     src, dst, out, edges, nodes);
    }
}